// Round 15
// baseline (150.033 us; speedup 1.0000x reference)
//
#include <hip/hip_runtime.h>
#include <hip/hip_bf16.h>

#define S_LEN 8192
#define DM    1024
#define DK    128
#define KSTR  136    // K LDS row stride (shorts): 2-way max bank aliasing
#define VSTR  72     // Vt LDS row stride (shorts)
#define ASTR  68     // proj LDS row stride (halves): 2-bank row shift
#define SLOTD 1056   // dwords per partial slot: m[16] l[16] fp32 + O[16*128] fp16

typedef __attribute__((ext_vector_type(8))) short bf16x8;
typedef __attribute__((ext_vector_type(8))) _Float16 f16x8;
typedef __attribute__((ext_vector_type(4))) float f32x4;

__device__ __forceinline__ f32x4 mfma16(bf16x8 a, bf16x8 b, f32x4 c) {
    return __builtin_amdgcn_mfma_f32_16x16x32_bf16(a, b, c, 0, 0, 0);
}
__device__ __forceinline__ f32x4 mfma16f(f16x8 a, f16x8 b, f32x4 c) {
    return __builtin_amdgcn_mfma_f32_16x16x32_f16(a, b, c, 0, 0, 0);
}

// fp32 -> bf16 (RNE)
__device__ __forceinline__ ushort f2bf(float f) {
    unsigned u = __builtin_bit_cast(unsigned, f);
    u += 0x7FFFu + ((u >> 16) & 1u);
    return (ushort)(u >> 16);
}

__device__ __forceinline__ ushort f2h(float f) {
    return __builtin_bit_cast(ushort, (_Float16)f);
}

// packed f32 pair -> bf16x2 in one u32 (lo = a, hi = b)
__device__ __forceinline__ uint cvt_pk_bf16(float a, float b) {
    uint r;
    asm("v_cvt_pk_bf16_f32 %0, %1, %2" : "=v"(r) : "v"(a), "v"(b));
    return r;
}

// ---------------------------------------------------------------------------
// fp32 -> fp16 conversion of Wq|Wk|Wv only (each 128x1024, 1.5 MB total).
// ---------------------------------------------------------------------------
__global__ __launch_bounds__(256, 1)
void convert_w_kernel(const float* __restrict__ Wq,
                      const float* __restrict__ Wk,
                      const float* __restrict__ Wv,
                      _Float16* __restrict__ Wh) {
    const int NW4 = DK * DM / 4;           // 32768 float4 per matrix
    const int i = blockIdx.x * 256 + threadIdx.x;   // grid 384 -> 98304 exact
    const int which = i / NW4;
    const int off = i - which * NW4;
    const float4 v = ((const float4*)(which == 0 ? Wq : (which == 1 ? Wk : Wv)))[off];
    union { _Float16 h[4]; uint2 u; } p;
    p.h[0] = (_Float16)v.x; p.h[1] = (_Float16)v.y;
    p.h[2] = (_Float16)v.z; p.h[3] = (_Float16)v.w;
    *(uint2*)(Wh + (size_t)which * (DK * DM) + (size_t)off * 4) = p.u;
}

// ---------------------------------------------------------------------------
// Projection GEMM v5: TLP test. Same r9 schedule (reg-prefetch, single LDS
// buffer, 2 barriers per BK=64 tile, 16 tiles) but BM=16: grid 512x3 = 1536
// blocks = 6 blocks/CU (24 waves/CU vs 12). LDS 19.6 KB. Theory: proj is
// latency-bound at 12 waves/CU (~5000 cy/iter vs ~600 cy issue work);
// doubling resident waves halves exposed latency.
// ---------------------------------------------------------------------------
__global__ __launch_bounds__(256)
void proj_gemm_kernel(const float* __restrict__ X,
                      const _Float16* __restrict__ Wh,
                      ushort* __restrict__ Qb,
                      ushort* __restrict__ Kb,
                      ushort* __restrict__ Vtb) {
    __shared__ _Float16 Ash[16 * ASTR];     // 2176 B
    __shared__ _Float16 Bsh[128 * ASTR];    // 17408 B (19584 total)

    const int tid  = threadIdx.x;
    const int lane = tid & 63;
    const int quad = lane >> 4;
    const int l15  = lane & 15;
    const int wv   = tid >> 6;              // wave owns cols [wv*32, wv*32+32)
    const int m0   = blockIdx.x * 16;
    const int nb   = blockIdx.y;
    const _Float16* Wbase = Wh + nb * (DK * DM);

    f32x4 acc[2];
#pragma unroll
    for (int ni = 0; ni < 2; ++ni) acc[ni] = (f32x4){0.f, 0.f, 0.f, 0.f};

    float4 sa;      // A: 16 rows x 16 granules(16B fp32) = 256 -> 1/thread
    f16x8 sb[4];    // B: 128 rows x 8 chunks(16B) = 1024 -> 4/thread

#define LOADR(KK)                                                              \
    {                                                                          \
        sa = *(const float4*)(X + (size_t)(m0 + (tid >> 4)) * DM + (KK) + (tid & 15) * 4); \
        _Pragma("unroll")                                                      \
        for (int i = 0; i < 4; ++i) {                                          \
            const int s = tid + (i << 8);                                      \
            sb[i] = *(const f16x8*)(Wbase + (size_t)(s >> 3) * DM + (KK) + (s & 7) * 8); \
        }                                                                      \
    }
#define WRITE_LDS()                                                            \
    {                                                                          \
        union { _Float16 h[4]; uint2 u; } pa_;                                 \
        pa_.h[0] = (_Float16)sa.x; pa_.h[1] = (_Float16)sa.y;                  \
        pa_.h[2] = (_Float16)sa.z; pa_.h[3] = (_Float16)sa.w;                  \
        *(uint2*)(Ash + (tid >> 4) * ASTR + (tid & 15) * 4) = pa_.u;           \
        _Pragma("unroll")                                                      \
        for (int i = 0; i < 4; ++i) {                                          \
            const int s = tid + (i << 8);                                      \
            *(f16x8*)(Bsh + (s >> 3) * ASTR + (s & 7) * 8) = sb[i];            \
        }                                                                      \
    }

    LOADR(0)
    for (int it = 0; it < 16; ++it) {
        __syncthreads();          // previous compute done reading LDS
        WRITE_LDS()
        if (it + 1 < 16) LOADR((it + 1) * 64)   // prefetch next into regs
        __syncthreads();          // staging visible

        __builtin_amdgcn_s_setprio(1);
#pragma unroll
        for (int kc = 0; kc < 2; ++kc) {
            const f16x8 af = *(const f16x8*)(Ash + l15 * ASTR + kc * 32 + quad * 8);
#pragma unroll
            for (int t = 0; t < 2; ++t) {
                const f16x8 bf = *(const f16x8*)(Bsh + (wv * 32 + t * 16 + l15) * ASTR + kc * 32 + quad * 8);
                acc[t] = mfma16f(af, bf, acc[t]);
            }
        }
        __builtin_amdgcn_s_setprio(0);
    }
#undef LOADR
#undef WRITE_LDS

    if (nb == 2) {
#pragma unroll
        for (int ni = 0; ni < 2; ++ni) {
            const int n = wv * 32 + ni * 16 + l15;
            const int m = m0 + quad * 4;
            union { ushort h[4]; uint2 u; } p;
#pragma unroll
            for (int r = 0; r < 4; ++r) p.h[r] = f2bf(acc[ni][r]);
            *(uint2*)(Vtb + (size_t)n * S_LEN + m) = p.u;
        }
    } else {
        ushort* Ob = (nb == 0) ? Qb : Kb;
        const float sc = (nb == 0) ? 0.088388347648318447f * 1.4426950408889634f : 1.0f;
#pragma unroll
        for (int ni = 0; ni < 2; ++ni) {
            const int n = wv * 32 + ni * 16 + l15;
#pragma unroll
            for (int r = 0; r < 4; ++r) {
                const int m = m0 + quad * 4 + r;
                Ob[(size_t)m * DK + n] = f2bf(acc[ni][r] * sc);
            }
        }
    }
}

// ---------------------------------------------------------------------------
// Flash attention partials — r2/r8 version VERBATIM (best measured, 45.4 us).
// This structure has defeated five alternatives (32x32, KVBLK=32, fused merge,
// K-from-global, finer chunks); do not modify.
// ---------------------------------------------------------------------------
__global__ __launch_bounds__(256, 3)
void flash_partial_kernel(const ushort* __restrict__ Qg,
                          const ushort* __restrict__ Kg,
                          const ushort* __restrict__ Vtg,
                          float* __restrict__ Part) {
    __shared__ __align__(16) ushort Ks [64 * KSTR];      // 17408 B
    __shared__ __align__(16) ushort Vts[128 * VSTR];     // 18432 B  (total 35840)

    // decode (qb, chunk): qb<8 -> qb+1 chunks (triangular, 36 blocks);
    // qb>=8 -> 8 chunks each (960 blocks). total 996.
    const int b = 995 - (int)blockIdx.x;   // heavy-first
    int qb, chunk;
    if (b < 36) {
        int q = 0;
        while (b >= (q + 1) * (q + 2) / 2) ++q;
        qb = q; chunk = b - q * (q + 1) / 2;
    } else {
        qb = 8 + ((b - 36) >> 3);
        chunk = (b - 36) & 7;
    }
    const int nkt   = qb + 1;
    const int NC    = nkt < 8 ? nkt : 8;
    const int kt_lo = chunk * nkt / NC;
    const int kt_hi = (chunk + 1) * nkt / NC;

    const int tid  = threadIdx.x;
    const int wv   = tid >> 6;
    const int lane = tid & 63;
    const int quad = lane >> 4;
    const int l15  = lane & 15;
    const int q0w  = qb * 64 + wv * 16;

    // Q fragments (B-operand layout == same per-lane pattern), resident
    bf16x8 qf[4];
    {
        const ushort* qrow = Qg + (size_t)(q0w + l15) * DK + quad * 8;
#pragma unroll
        for (int kc = 0; kc < 4; ++kc) qf[kc] = *(const bf16x8*)(qrow + kc * 32);
    }

    // per-lane row state: this lane's q-row is q0w + l15 (dup across quads)
    float m_ = -__builtin_inff();
    float l_ = 0.f;
    f32x4 acc[8];
#pragma unroll
    for (int d = 0; d < 8; ++d) acc[d] = (f32x4){0.f, 0.f, 0.f, 0.f};

    bf16x8 stg[8];
#define LOAD_TILE(K0)                                                          \
    {                                                                          \
        const int k0_ = (K0);                                                  \
        _Pragma("unroll")                                                      \
        for (int i = 0; i < 8; ++i) {                                          \
            const int c = tid + (i << 8);                                      \
            if (c < 1024) {                                                    \
                const int row = c >> 4, ch = c & 15;                           \
                stg[i] = *(const bf16x8*)(Kg + (size_t)(k0_ + row) * DK + ch * 8); \
            } else {                                                           \
                const int cc = c - 1024;                                       \
                const int row = cc >> 3, ch = cc & 7;                          \
                stg[i] = *(const bf16x8*)(Vtg + (size_t)row * S_LEN + k0_ + ch * 8); \
            }                                                                  \
        }                                                                      \
    }

    LOAD_TILE(kt_lo * 64)

    for (int kt = kt_lo; kt < kt_hi; ++kt) {
        const int k0 = kt * 64;

        __syncthreads();   // previous tile's frag reads complete
#pragma unroll
        for (int i = 0; i < 8; ++i) {
            const int c = tid + (i << 8);
            if (c < 1024) {
                const int row = c >> 4, ch = c & 15;
                *(bf16x8*)(Ks + row * KSTR + ch * 8) = stg[i];
            } else {
                // V: store k-permuted.  chunk ch covers local k = ch*8+m;
                // slot s_lo = (ch>>2)*32 + (ch&1)*16 + ((ch>>1)&1)*4 (m 0..3),
                // +8 for m 4..7.  Two b64 writes.
                const int cc = c - 1024;
                const int row = cc >> 3, ch = cc & 7;
                const int s_lo = ((ch >> 2) << 5) + ((ch & 1) << 4) + (((ch >> 1) & 1) << 2);
                union { bf16x8 v; uint2 q2[2]; } u;
                u.v = stg[i];
                ushort* vb = Vts + row * VSTR + s_lo;
                *(uint2*)vb       = u.q2[0];
                *(uint2*)(vb + 8) = u.q2[1];
            }
        }
        if (kt + 1 < kt_hi) LOAD_TILE((kt + 1) * 64)   // prefetch into regs
        __syncthreads();   // staging visible to all waves

        // ---- S^T = K Q^T (64 x 16): lane holds S[k = k0+nb*16+quad*4+r][q = q0w+l15]
        f32x4 Sr[4];
        __builtin_amdgcn_s_setprio(1);
#pragma unroll
        for (int nb = 0; nb < 4; ++nb) {
            Sr[nb] = (f32x4){0.f, 0.f, 0.f, 0.f};
            const ushort* kb = Ks + (nb * 16 + l15) * KSTR + quad * 8;
#pragma unroll
            for (int kc = 0; kc < 4; ++kc)
                Sr[nb] = mfma16(*(const bf16x8*)(kb + kc * 32), qf[kc], Sr[nb]);
        }
        __builtin_amdgcn_s_setprio(0);

        // ---- causal mask (diagonal tiles only) ----
        if (k0 + 63 > q0w) {
            const int qg = q0w + l15;
#pragma unroll
            for (int nb = 0; nb < 4; ++nb) {
                const int kg = k0 + nb * 16 + quad * 4;
#pragma unroll
                for (int r = 0; r < 4; ++r)
                    if (kg + r > qg) Sr[nb][r] = -__builtin_inff();
            }
        }

        // ---- online softmax, fully in-register ----
        float pmax;
        {
            float a0 = fmaxf(fmaxf(Sr[0][0], Sr[0][1]), fmaxf(Sr[0][2], Sr[0][3]));
            float a1 = fmaxf(fmaxf(Sr[1][0], Sr[1][1]), fmaxf(Sr[1][2], Sr[1][3]));
            float a2 = fmaxf(fmaxf(Sr[2][0], Sr[2][1]), fmaxf(Sr[2][2], Sr[2][3]));
            float a3 = fmaxf(fmaxf(Sr[3][0], Sr[3][1]), fmaxf(Sr[3][2], Sr[3][3]));
            pmax = fmaxf(fmaxf(a0, a1), fmaxf(a2, a3));
            pmax = fmaxf(pmax, __shfl_xor(pmax, 16));
            pmax = fmaxf(pmax, __shfl_xor(pmax, 32));
        }
        // defer-max: rescale only when some row's max grew past threshold 8
        if (__any(pmax > m_ + 8.f)) {
            const float mnew = fmaxf(m_, pmax);
            const float al = __builtin_amdgcn_exp2f(m_ - mnew);   // 0 on first tile
            m_ = mnew;
            l_ *= al;
            float alr[4];
#pragma unroll
            for (int r = 0; r < 4; ++r)
                alr[r] = __shfl(al, (lane & 48) | (((lane >> 4) & 3) * 4 + r));
#pragma unroll
            for (int d = 0; d < 8; ++d)
#pragma unroll
                for (int r = 0; r < 4; ++r) acc[d][r] *= alr[r];
        }

        float p[4][4];
        float rs = 0.f;
#pragma unroll
        for (int nb = 0; nb < 4; ++nb)
#pragma unroll
            for (int r = 0; r < 4; ++r) {
                p[nb][r] = __builtin_amdgcn_exp2f(Sr[nb][r] - m_);
                rs += p[nb][r];
            }
        rs += __shfl_xor(rs, 16);
        rs += __shfl_xor(rs, 32);
        l_ += rs;

        // ---- O += P V, P A-frags built locally via the k-permutation ----
        __builtin_amdgcn_s_setprio(1);
#pragma unroll
        for (int kcp = 0; kcp < 2; ++kcp) {
            union { uint u[4]; bf16x8 v; } pf;
            pf.u[0] = cvt_pk_bf16(p[2 * kcp][0],     p[2 * kcp][1]);
            pf.u[1] = cvt_pk_bf16(p[2 * kcp][2],     p[2 * kcp][3]);
            pf.u[2] = cvt_pk_bf16(p[2 * kcp + 1][0], p[2 * kcp + 1][1]);
            pf.u[3] = cvt_pk_bf16(p[2 * kcp + 1][2], p[2 * kcp + 1][3]);
#pragma unroll
            for (int db = 0; db < 8; ++db) {
                const bf16x8 vf = *(const bf16x8*)(Vts + (db * 16 + l15) * VSTR + kcp * 32 + quad * 8);
                acc[db] = mfma16(pf.v, vf, acc[db]);
            }
        }
        __builtin_amdgcn_s_setprio(0);
    }
#undef LOAD_TILE

    // ---- write partial slot (wave-private, no merge needed) ----
    const int qt16 = qb * 4 + wv;
    float* slot = Part + (size_t)(qt16 * 8 + chunk) * SLOTD;
    if (quad == 0) {
        slot[l15]      = m_;
        slot[16 + l15] = l_;
    }
    // O as fp16: pair lanes (l15 even/odd -> dims d, d+1) into one dword
    uint* slotO = (uint*)(slot + 32);
#pragma unroll
    for (int d = 0; d < 8; ++d)
#pragma unroll
        for (int r = 0; r < 4; ++r) {
            const float v  = acc[d][r];
            const float vp = __shfl_xor(v, 1);
            if ((l15 & 1) == 0) {
                const int row = quad * 4 + r;
                const uint u = (uint)f2h(v) | ((uint)f2h(vp) << 16);
                slotO[(row * 128 + d * 16 + l15) >> 1] = u;
            }
        }
}

// ---------------------------------------------------------------------------
// Merge partials per 16-row q-tile, normalize, write output.
// P = min(8, qb+1), consistent with flash's NC.
// ---------------------------------------------------------------------------
__global__ __launch_bounds__(256)
void flash_merge_kernel(const float* __restrict__ Part, float* __restrict__ Out) {
    __shared__ float Ms[16], Ls[16];
    __shared__ float Sc[8][16];
    const int qt = blockIdx.x;
    const int q0 = qt * 16;
    const int qb = qt >> 2;
    const int P  = (qb + 1 < 8) ? (qb + 1) : 8;
    const int tid = threadIdx.x;
    const float* base = Part + (size_t)qt * 8 * SLOTD;

    if (tid < 16) {
        float M = -__builtin_inff();
        for (int p = 0; p < P; ++p) M = fmaxf(M, base[p * SLOTD + tid]);
        float L = 0.f;
        for (int p = 0; p < P; ++p)
            L += base[p * SLOTD + 16 + tid] * exp2f(base[p * SLOTD + tid] - M);
        Ms[tid] = M; Ls[tid] = L;
    }
    __syncthreads();
    if (tid < 128) {
        const int p = tid >> 4, row = tid & 15;
        Sc[p][row] = (p < P) ? exp2f(base[p * SLOTD + row] - Ms[row]) : 0.f;
    }
    __syncthreads();

    // 16 rows x 64 dword-pairs (2 fp16 cols each) = 1024 items, 4 per thread
#pragma unroll
    for (int j = tid; j < 1024; j += 256) {
        const int row = j >> 6, c2 = j & 63;
        float o0 = 0.f, o1 = 0.f;
        for (int p = 0; p < P; ++p) {
            const uint u = ((const uint*)(base + p * SLOTD + 32))[row * 64 + c2];
            const float sc = Sc[p][row];
            o0 += (float)__builtin_bit_cast(_Float16, (ushort)(u & 0xFFFF)) * sc;
            o1 += (float)__builtin_bit_cast(_Float16, (ushort)(u >> 16)) * sc;
        }
        const float inv = 1.0f / Ls[row];
        float2 o; o.x = o0 * inv; o.y = o1 * inv;
        *(float2*)(Out + (size_t)(q0 + row) * DK + c2 * 2) = o;
    }
}

extern "C" void kernel_launch(void* const* d_in, const int* in_sizes, int n_in,
                              void* d_out, int out_size, void* d_ws, size_t ws_size,
                              hipStream_t stream) {
    const float* X  = (const float*)d_in[0];
    const float* Wq = (const float*)d_in[1];
    const float* Wk = (const float*)d_in[2];
    const float* Wv = (const float*)d_in[3];
    ushort* ws  = (ushort*)d_ws;
    ushort* Qb  = ws;                          // 8192x128 bf16 (pre-scaled)
    ushort* Kb  = ws + (size_t)S_LEN * DK;     // 8192x128 bf16
    ushort* Vtb = ws + 2 * (size_t)S_LEN * DK; // 128x8192 bf16 (transposed)
    _Float16* Wh = (_Float16*)(ws + 3 * (size_t)S_LEN * DK);  // 384x1024 fp16
    // Partials after Wh: 512 qtiles * 8 slots * 4224 B = 17.3 MiB
    float* Part = (float*)(Wh + (size_t)3 * DK * DM);
    float* Out = (float*)d_out;

    convert_w_kernel<<<384, 256, 0, stream>>>(Wq, Wk, Wv, Wh);
    proj_gemm_kernel<<<dim3(512, 3), 256, 0, stream>>>(X, Wh, Qb, Kb, Vtb);
    flash_partial_kernel<<<996, 256, 0, stream>>>(Qb, Kb, Vtb, Part);
    flash_merge_kernel<<<512, 256, 0, stream>>>(Part, Out);
}

// Round 16
// 143.443 us; speedup vs baseline: 1.0459x; 1.0459x over previous
//
#include <hip/hip_runtime.h>
#include <hip/hip_bf16.h>

#define S_LEN 8192
#define DM    1024
#define DK    128
#define KSTR  136    // K LDS row stride (shorts): 2-way max bank aliasing
#define VSTR  72     // Vt LDS row stride (shorts)
#define ASTR  68     // proj LDS row stride (halves): 2-bank row shift
#define SLOTD 1056   // dwords per partial slot: m[16] l[16] fp32 + O[16*128] fp16

typedef __attribute__((ext_vector_type(8))) short bf16x8;
typedef __attribute__((ext_vector_type(8))) _Float16 f16x8;
typedef __attribute__((ext_vector_type(4))) float f32x4;

__device__ __forceinline__ f32x4 mfma16(bf16x8 a, bf16x8 b, f32x4 c) {
    return __builtin_amdgcn_mfma_f32_16x16x32_bf16(a, b, c, 0, 0, 0);
}
__device__ __forceinline__ f32x4 mfma16f(f16x8 a, f16x8 b, f32x4 c) {
    return __builtin_amdgcn_mfma_f32_16x16x32_f16(a, b, c, 0, 0, 0);
}

// fp32 -> bf16 (RNE)
__device__ __forceinline__ ushort f2bf(float f) {
    unsigned u = __builtin_bit_cast(unsigned, f);
    u += 0x7FFFu + ((u >> 16) & 1u);
    return (ushort)(u >> 16);
}

__device__ __forceinline__ ushort f2h(float f) {
    return __builtin_bit_cast(ushort, (_Float16)f);
}

// packed f32 pair -> bf16x2 in one u32 (lo = a, hi = b)
__device__ __forceinline__ uint cvt_pk_bf16(float a, float b) {
    uint r;
    asm("v_cvt_pk_bf16_f32 %0, %1, %2" : "=v"(r) : "v"(a), "v"(b));
    return r;
}

// ---------------------------------------------------------------------------
// fp32 -> fp16 conversion of Wq|Wk|Wv only (each 128x1024, 1.5 MB total).
// X is NOT pre-converted: proj reads it fp32 and converts in-register.
// ---------------------------------------------------------------------------
__global__ __launch_bounds__(256, 1)
void convert_w_kernel(const float* __restrict__ Wq,
                      const float* __restrict__ Wk,
                      const float* __restrict__ Wv,
                      _Float16* __restrict__ Wh) {
    const int NW4 = DK * DM / 4;           // 32768 float4 per matrix
    const int i = blockIdx.x * 256 + threadIdx.x;   // grid 384 -> 98304 exact
    const int which = i / NW4;
    const int off = i - which * NW4;
    const float4 v = ((const float4*)(which == 0 ? Wq : (which == 1 ? Wk : Wv)))[off];
    union { _Float16 h[4]; uint2 u; } p;
    p.h[0] = (_Float16)v.x; p.h[1] = (_Float16)v.y;
    p.h[2] = (_Float16)v.z; p.h[3] = (_Float16)v.w;
    *(uint2*)(Wh + (size_t)which * (DK * DM) + (size_t)off * 4) = p.u;
}

// ---------------------------------------------------------------------------
// Projection GEMM v2 (r9 measured-best): 3 passes (grid 256 x 3), BM=32,
// BN=128, BK=64, 16 iters. Flash-style staging: B (fp16 Wh, L2-resident) and
// A (fp32 X, converted in-register) REG-prefetched for tile k+1 during
// compute of tile k. Per iter: 2 barriers, 8 MFMA/wave. LDS 21.8 KB.
// Measured ~34 us; resisted dbuf / BM=16-TLP / fp32-W variants (all +-2 us).
// ---------------------------------------------------------------------------
__global__ __launch_bounds__(256)
void proj_gemm_kernel(const float* __restrict__ X,
                      const _Float16* __restrict__ Wh,
                      ushort* __restrict__ Qb,
                      ushort* __restrict__ Kb,
                      ushort* __restrict__ Vtb) {
    __shared__ _Float16 Ash[32 * ASTR];     // 4352 B
    __shared__ _Float16 Bsh[128 * ASTR];    // 17408 B

    const int tid  = threadIdx.x;
    const int lane = tid & 63;
    const int quad = lane >> 4;
    const int l15  = lane & 15;
    const int wv   = tid >> 6;
    const int wm   = wv & 1;    // m-half (16 rows)
    const int wn   = wv >> 1;   // n-half (64 cols)
    const int m0   = blockIdx.x * 32;
    const int nb   = blockIdx.y;
    const _Float16* Wbase = Wh + nb * (DK * DM);

    f32x4 acc[4];
#pragma unroll
    for (int ni = 0; ni < 4; ++ni) acc[ni] = (f32x4){0.f, 0.f, 0.f, 0.f};

    float4 sa[2];   // A: 32 rows x 16 granules(16B) = 512 -> 2/thread
    f16x8 sb[4];    // B: 128 rows x 8 chunks(16B)  = 1024 -> 4/thread

#define LOADR(KK)                                                              \
    {                                                                          \
        _Pragma("unroll")                                                      \
        for (int i = 0; i < 2; ++i) {                                          \
            const int s = tid + (i << 8);                                      \
            sa[i] = *(const float4*)(X + (size_t)(m0 + (s >> 4)) * DM + (KK) + (s & 15) * 4); \
        }                                                                      \
        _Pragma("unroll")                                                      \
        for (int i = 0; i < 4; ++i) {                                          \
            const int s = tid + (i << 8);                                      \
            sb[i] = *(const f16x8*)(Wbase + (size_t)(s >> 3) * DM + (KK) + (s & 7) * 8); \
        }                                                                      \
    }
#define WRITE_LDS()                                                            \
    {                                                                          \
        _Pragma("unroll")                                                      \
        for (int i = 0; i < 2; ++i) {                                          \
            const int s = tid + (i << 8);                                      \
            union { _Float16 h[4]; uint2 u; } pa_;                             \
            pa_.h[0] = (_Float16)sa[i].x; pa_.h[1] = (_Float16)sa[i].y;        \
            pa_.h[2] = (_Float16)sa[i].z; pa_.h[3] = (_Float16)sa[i].w;        \
            *(uint2*)(Ash + (s >> 4) * ASTR + (s & 15) * 4) = pa_.u;           \
        }                                                                      \
        _Pragma("unroll")                                                      \
        for (int i = 0; i < 4; ++i) {                                          \
            const int s = tid + (i << 8);                                      \
            *(f16x8*)(Bsh + (s >> 3) * ASTR + (s & 7) * 8) = sb[i];            \
        }                                                                      \
    }

    LOADR(0)
    for (int it = 0; it < 16; ++it) {
        __syncthreads();          // previous compute done reading LDS
        WRITE_LDS()
        if (it + 1 < 16) LOADR((it + 1) * 64)   // prefetch next into regs
        __syncthreads();          // staging visible

        __builtin_amdgcn_s_setprio(1);
#pragma unroll
        for (int kc = 0; kc < 2; ++kc) {
            const f16x8 af = *(const f16x8*)(Ash + (wm * 16 + l15) * ASTR + kc * 32 + quad * 8);
#pragma unroll
            for (int t = 0; t < 4; ++t) {
                const f16x8 bf = *(const f16x8*)(Bsh + (wn * 64 + t * 16 + l15) * ASTR + kc * 32 + quad * 8);
                acc[t] = mfma16f(af, bf, acc[t]);
            }
        }
        __builtin_amdgcn_s_setprio(0);
    }
#undef LOADR
#undef WRITE_LDS

    if (nb == 2) {
#pragma unroll
        for (int ni = 0; ni < 4; ++ni) {
            const int n = wn * 64 + ni * 16 + l15;
            const int m = m0 + wm * 16 + quad * 4;
            union { ushort h[4]; uint2 u; } p;
#pragma unroll
            for (int r = 0; r < 4; ++r) p.h[r] = f2bf(acc[ni][r]);
            *(uint2*)(Vtb + (size_t)n * S_LEN + m) = p.u;
        }
    } else {
        ushort* Ob = (nb == 0) ? Qb : Kb;
        const float sc = (nb == 0) ? 0.088388347648318447f * 1.4426950408889634f : 1.0f;
#pragma unroll
        for (int ni = 0; ni < 4; ++ni) {
            const int n = wn * 64 + ni * 16 + l15;
#pragma unroll
            for (int r = 0; r < 4; ++r) {
                const int m = m0 + wm * 16 + quad * 4 + r;
                Ob[(size_t)m * DK + n] = f2bf(acc[ni][r] * sc);
            }
        }
    }
}

// ---------------------------------------------------------------------------
// Flash attention partials — r2/r8 version VERBATIM (best measured, 45.4 us).
// This structure has defeated five alternatives (32x32, KVBLK=32, fused merge,
// K-from-global, finer chunks); do not modify.
// ---------------------------------------------------------------------------
__global__ __launch_bounds__(256, 3)
void flash_partial_kernel(const ushort* __restrict__ Qg,
                          const ushort* __restrict__ Kg,
                          const ushort* __restrict__ Vtg,
                          float* __restrict__ Part) {
    __shared__ __align__(16) ushort Ks [64 * KSTR];      // 17408 B
    __shared__ __align__(16) ushort Vts[128 * VSTR];     // 18432 B  (total 35840)

    // decode (qb, chunk): qb<8 -> qb+1 chunks (triangular, 36 blocks);
    // qb>=8 -> 8 chunks each (960 blocks). total 996.
    const int b = 995 - (int)blockIdx.x;   // heavy-first
    int qb, chunk;
    if (b < 36) {
        int q = 0;
        while (b >= (q + 1) * (q + 2) / 2) ++q;
        qb = q; chunk = b - q * (q + 1) / 2;
    } else {
        qb = 8 + ((b - 36) >> 3);
        chunk = (b - 36) & 7;
    }
    const int nkt   = qb + 1;
    const int NC    = nkt < 8 ? nkt : 8;
    const int kt_lo = chunk * nkt / NC;
    const int kt_hi = (chunk + 1) * nkt / NC;

    const int tid  = threadIdx.x;
    const int wv   = tid >> 6;
    const int lane = tid & 63;
    const int quad = lane >> 4;
    const int l15  = lane & 15;
    const int q0w  = qb * 64 + wv * 16;

    // Q fragments (B-operand layout == same per-lane pattern), resident
    bf16x8 qf[4];
    {
        const ushort* qrow = Qg + (size_t)(q0w + l15) * DK + quad * 8;
#pragma unroll
        for (int kc = 0; kc < 4; ++kc) qf[kc] = *(const bf16x8*)(qrow + kc * 32);
    }

    // per-lane row state: this lane's q-row is q0w + l15 (dup across quads)
    float m_ = -__builtin_inff();
    float l_ = 0.f;
    f32x4 acc[8];
#pragma unroll
    for (int d = 0; d < 8; ++d) acc[d] = (f32x4){0.f, 0.f, 0.f, 0.f};

    bf16x8 stg[8];
#define LOAD_TILE(K0)                                                          \
    {                                                                          \
        const int k0_ = (K0);                                                  \
        _Pragma("unroll")                                                      \
        for (int i = 0; i < 8; ++i) {                                          \
            const int c = tid + (i << 8);                                      \
            if (c < 1024) {                                                    \
                const int row = c >> 4, ch = c & 15;                           \
                stg[i] = *(const bf16x8*)(Kg + (size_t)(k0_ + row) * DK + ch * 8); \
            } else {                                                           \
                const int cc = c - 1024;                                       \
                const int row = cc >> 3, ch = cc & 7;                          \
                stg[i] = *(const bf16x8*)(Vtg + (size_t)row * S_LEN + k0_ + ch * 8); \
            }                                                                  \
        }                                                                      \
    }

    LOAD_TILE(kt_lo * 64)

    for (int kt = kt_lo; kt < kt_hi; ++kt) {
        const int k0 = kt * 64;

        __syncthreads();   // previous tile's frag reads complete
#pragma unroll
        for (int i = 0; i < 8; ++i) {
            const int c = tid + (i << 8);
            if (c < 1024) {
                const int row = c >> 4, ch = c & 15;
                *(bf16x8*)(Ks + row * KSTR + ch * 8) = stg[i];
            } else {
                // V: store k-permuted.  chunk ch covers local k = ch*8+m;
                // slot s_lo = (ch>>2)*32 + (ch&1)*16 + ((ch>>1)&1)*4 (m 0..3),
                // +8 for m 4..7.  Two b64 writes.
                const int cc = c - 1024;
                const int row = cc >> 3, ch = cc & 7;
                const int s_lo = ((ch >> 2) << 5) + ((ch & 1) << 4) + (((ch >> 1) & 1) << 2);
                union { bf16x8 v; uint2 q2[2]; } u;
                u.v = stg[i];
                ushort* vb = Vts + row * VSTR + s_lo;
                *(uint2*)vb       = u.q2[0];
                *(uint2*)(vb + 8) = u.q2[1];
            }
        }
        if (kt + 1 < kt_hi) LOAD_TILE((kt + 1) * 64)   // prefetch into regs
        __syncthreads();   // staging visible to all waves

        // ---- S^T = K Q^T (64 x 16): lane holds S[k = k0+nb*16+quad*4+r][q = q0w+l15]
        f32x4 Sr[4];
        __builtin_amdgcn_s_setprio(1);
#pragma unroll
        for (int nb = 0; nb < 4; ++nb) {
            Sr[nb] = (f32x4){0.f, 0.f, 0.f, 0.f};
            const ushort* kb = Ks + (nb * 16 + l15) * KSTR + quad * 8;
#pragma unroll
            for (int kc = 0; kc < 4; ++kc)
                Sr[nb] = mfma16(*(const bf16x8*)(kb + kc * 32), qf[kc], Sr[nb]);
        }
        __builtin_amdgcn_s_setprio(0);

        // ---- causal mask (diagonal tiles only) ----
        if (k0 + 63 > q0w) {
            const int qg = q0w + l15;
#pragma unroll
            for (int nb = 0; nb < 4; ++nb) {
                const int kg = k0 + nb * 16 + quad * 4;
#pragma unroll
                for (int r = 0; r < 4; ++r)
                    if (kg + r > qg) Sr[nb][r] = -__builtin_inff();
            }
        }

        // ---- online softmax, fully in-register ----
        float pmax;
        {
            float a0 = fmaxf(fmaxf(Sr[0][0], Sr[0][1]), fmaxf(Sr[0][2], Sr[0][3]));
            float a1 = fmaxf(fmaxf(Sr[1][0], Sr[1][1]), fmaxf(Sr[1][2], Sr[1][3]));
            float a2 = fmaxf(fmaxf(Sr[2][0], Sr[2][1]), fmaxf(Sr[2][2], Sr[2][3]));
            float a3 = fmaxf(fmaxf(Sr[3][0], Sr[3][1]), fmaxf(Sr[3][2], Sr[3][3]));
            pmax = fmaxf(fmaxf(a0, a1), fmaxf(a2, a3));
            pmax = fmaxf(pmax, __shfl_xor(pmax, 16));
            pmax = fmaxf(pmax, __shfl_xor(pmax, 32));
        }
        // defer-max: rescale only when some row's max grew past threshold 8
        if (__any(pmax > m_ + 8.f)) {
            const float mnew = fmaxf(m_, pmax);
            const float al = __builtin_amdgcn_exp2f(m_ - mnew);   // 0 on first tile
            m_ = mnew;
            l_ *= al;
            float alr[4];
#pragma unroll
            for (int r = 0; r < 4; ++r)
                alr[r] = __shfl(al, (lane & 48) | (((lane >> 4) & 3) * 4 + r));
#pragma unroll
            for (int d = 0; d < 8; ++d)
#pragma unroll
                for (int r = 0; r < 4; ++r) acc[d][r] *= alr[r];
        }

        float p[4][4];
        float rs = 0.f;
#pragma unroll
        for (int nb = 0; nb < 4; ++nb)
#pragma unroll
            for (int r = 0; r < 4; ++r) {
                p[nb][r] = __builtin_amdgcn_exp2f(Sr[nb][r] - m_);
                rs += p[nb][r];
            }
        rs += __shfl_xor(rs, 16);
        rs += __shfl_xor(rs, 32);
        l_ += rs;

        // ---- O += P V, P A-frags built locally via the k-permutation ----
        __builtin_amdgcn_s_setprio(1);
#pragma unroll
        for (int kcp = 0; kcp < 2; ++kcp) {
            union { uint u[4]; bf16x8 v; } pf;
            pf.u[0] = cvt_pk_bf16(p[2 * kcp][0],     p[2 * kcp][1]);
            pf.u[1] = cvt_pk_bf16(p[2 * kcp][2],     p[2 * kcp][3]);
            pf.u[2] = cvt_pk_bf16(p[2 * kcp + 1][0], p[2 * kcp + 1][1]);
            pf.u[3] = cvt_pk_bf16(p[2 * kcp + 1][2], p[2 * kcp + 1][3]);
#pragma unroll
            for (int db = 0; db < 8; ++db) {
                const bf16x8 vf = *(const bf16x8*)(Vts + (db * 16 + l15) * VSTR + kcp * 32 + quad * 8);
                acc[db] = mfma16(pf.v, vf, acc[db]);
            }
        }
        __builtin_amdgcn_s_setprio(0);
    }
#undef LOAD_TILE

    // ---- write partial slot (wave-private, no merge needed) ----
    const int qt16 = qb * 4 + wv;
    float* slot = Part + (size_t)(qt16 * 8 + chunk) * SLOTD;
    if (quad == 0) {
        slot[l15]      = m_;
        slot[16 + l15] = l_;
    }
    // O as fp16: pair lanes (l15 even/odd -> dims d, d+1) into one dword
    uint* slotO = (uint*)(slot + 32);
#pragma unroll
    for (int d = 0; d < 8; ++d)
#pragma unroll
        for (int r = 0; r < 4; ++r) {
            const float v  = acc[d][r];
            const float vp = __shfl_xor(v, 1);
            if ((l15 & 1) == 0) {
                const int row = quad * 4 + r;
                const uint u = (uint)f2h(v) | ((uint)f2h(vp) << 16);
                slotO[(row * 128 + d * 16 + l15) >> 1] = u;
            }
        }
}

// ---------------------------------------------------------------------------
// Merge partials per 16-row q-tile, normalize, write output.
// P = min(8, qb+1), consistent with flash's NC.
// ---------------------------------------------------------------------------
__global__ __launch_bounds__(256)
void flash_merge_kernel(const float* __restrict__ Part, float* __restrict__ Out) {
    __shared__ float Ms[16], Ls[16];
    __shared__ float Sc[8][16];
    const int qt = blockIdx.x;
    const int q0 = qt * 16;
    const int qb = qt >> 2;
    const int P  = (qb + 1 < 8) ? (qb + 1) : 8;
    const int tid = threadIdx.x;
    const float* base = Part + (size_t)qt * 8 * SLOTD;

    if (tid < 16) {
        float M = -__builtin_inff();
        for (int p = 0; p < P; ++p) M = fmaxf(M, base[p * SLOTD + tid]);
        float L = 0.f;
        for (int p = 0; p < P; ++p)
            L += base[p * SLOTD + 16 + tid] * exp2f(base[p * SLOTD + tid] - M);
        Ms[tid] = M; Ls[tid] = L;
    }
    __syncthreads();
    if (tid < 128) {
        const int p = tid >> 4, row = tid & 15;
        Sc[p][row] = (p < P) ? exp2f(base[p * SLOTD + row] - Ms[row]) : 0.f;
    }
    __syncthreads();

    // 16 rows x 64 dword-pairs (2 fp16 cols each) = 1024 items, 4 per thread
#pragma unroll
    for (int j = tid; j < 1024; j += 256) {
        const int row = j >> 6, c2 = j & 63;
        float o0 = 0.f, o1 = 0.f;
        for (int p = 0; p < P; ++p) {
            const uint u = ((const uint*)(base + p * SLOTD + 32))[row * 64 + c2];
            const float sc = Sc[p][row];
            o0 += (float)__builtin_bit_cast(_Float16, (ushort)(u & 0xFFFF)) * sc;
            o1 += (float)__builtin_bit_cast(_Float16, (ushort)(u >> 16)) * sc;
        }
        const float inv = 1.0f / Ls[row];
        float2 o; o.x = o0 * inv; o.y = o1 * inv;
        *(float2*)(Out + (size_t)(q0 + row) * DK + c2 * 2) = o;
    }
}

extern "C" void kernel_launch(void* const* d_in, const int* in_sizes, int n_in,
                              void* d_out, int out_size, void* d_ws, size_t ws_size,
                              hipStream_t stream) {
    const float* X  = (const float*)d_in[0];
    const float* Wq = (const float*)d_in[1];
    const float* Wk = (const float*)d_in[2];
    const float* Wv = (const float*)d_in[3];
    ushort* ws  = (ushort*)d_ws;
    ushort* Qb  = ws;                          // 8192x128 bf16 (pre-scaled)
    ushort* Kb  = ws + (size_t)S_LEN * DK;     // 8192x128 bf16
    ushort* Vtb = ws + 2 * (size_t)S_LEN * DK; // 128x8192 bf16 (transposed)
    _Float16* Wh = (_Float16*)(ws + 3 * (size_t)S_LEN * DK);  // 384x1024 fp16
    // Partials after Wh: 512 qtiles * 8 slots * 4224 B = 17.3 MiB
    float* Part = (float*)(Wh + (size_t)3 * DK * DM);
    float* Out = (float*)d_out;

    convert_w_kernel<<<384, 256, 0, stream>>>(Wq, Wk, Wv, Wh);
    proj_gemm_kernel<<<dim3(256, 3), 256, 0, stream>>>(X, Wh, Qb, Kb, Vtb);
    flash_partial_kernel<<<996, 256, 0, stream>>>(Qb, Kb, Vtb, Part);
    flash_merge_kernel<<<512, 256, 0, stream>>>(Part, Out);
}